// Round 3
// baseline (10477.914 us; speedup 1.0000x reference)
//
#include <hip/hip_runtime.h>

// AdaptiveDownsampling: farthest point sampling (B=8, N=8192, m=4096) + gather.
// Outputs concatenated flat: dp [8,4096,3] then df [8,4096,256], float32.
//
// Round-2 finding: two different bit-exact fp32 implementations produced the
// IDENTICAL mismatch (absmax 1.0508) vs the harness np reference -> the np
// reference computes in float64. Selection chain below is float64-exact.

#define BATCH 8
#define NPTS  8192
#define MSEL  4096
#define NFEAT 256
#define BLOCK 1024
#define PPT   8        // points per thread = NPTS / BLOCK

// fp64 square, opaque to the compiler so no v_fma_f64 contraction can merge
// the following adds (numpy float64 does separate mul / add / add).
__device__ __forceinline__ double sqd(double x) {
    double r;
    asm("v_mul_f64 %0, %1, %1" : "=v"(r) : "v"(x));
    return r;
}

__launch_bounds__(BLOCK, 1)
__global__ void fps_kernel(const float* __restrict__ pts,   // [B, N, 3]
                           float* __restrict__ dp,          // [B, M, 3]
                           int* __restrict__ idx_out)       // [B, M]
{
    const int b   = blockIdx.x;
    const int tid = threadIdx.x;
    const float* p = pts + (size_t)b * NPTS * 3;

    __shared__ double s_wv[16];
    __shared__ int    s_wi[16];
    __shared__ int    s_widx;
    __shared__ float  s_cx, s_cy, s_cz;

    // All points + running min-distance live in registers, as fp64
    // (fp32->fp64 conversion is exact; all subsequent arithmetic matches
    // numpy float64 bit-for-bit).
    double px[PPT], py[PPT], pz[PPT], mind[PPT];
#pragma unroll
    for (int j = 0; j < PPT; ++j) {
        const int n = tid + (j << 10);
        px[j]   = (double)p[n * 3 + 0];
        py[j]   = (double)p[n * 3 + 1];
        pz[j]   = (double)p[n * 3 + 2];
        mind[j] = 1e10;
    }

    // Selection 0 is point 0 (deterministic start).
    float cxf = p[0], cyf = p[1], czf = p[2];
    if (tid == 0) {
        dp[(size_t)b * MSEL * 3 + 0] = cxf;
        dp[(size_t)b * MSEL * 3 + 1] = cyf;
        dp[(size_t)b * MSEL * 3 + 2] = czf;
        idx_out[b * MSEL + 0] = 0;
    }

    const int lane = tid & 63;
    const int wid  = tid >> 6;

    double cx = (double)cxf, cy = (double)cyf, cz = (double)czf;

    for (int k = 1; k < MSEL; ++k) {
        // --- fp64 distance update + thread-local argmax (ascending idx, strict >) ---
        double bv = -1.0;
        int    bi = 0x7fffffff;
#pragma unroll
        for (int j = 0; j < PPT; ++j) {
            const double dx = px[j] - cx;
            const double dy = py[j] - cy;
            const double dz = pz[j] - cz;
            const double d  = (sqd(dx) + sqd(dy)) + sqd(dz);  // ((x^2+y^2)+z^2)
            const double m  = fmin(mind[j], d);
            mind[j] = m;
            if (m > bv) { bv = m; bi = tid + (j << 10); }
        }

        // --- wave64 reduce: lexicographic (max value, then min index) ---
#pragma unroll
        for (int off = 1; off < 64; off <<= 1) {
            const double ov = __shfl_xor(bv, off);
            const int    oi = __shfl_xor(bi, off);
            if (ov > bv || (ov == bv && oi < bi)) { bv = ov; bi = oi; }
        }
        if (lane == 0) { s_wv[wid] = bv; s_wi[wid] = bi; }
        __syncthreads();

        // --- cross-wave reduce on wave 0 (16 partials) ---
        if (wid == 0) {
            double v = (lane < 16) ? s_wv[lane] : -1.0;
            int    i = (lane < 16) ? s_wi[lane] : 0x7fffffff;
#pragma unroll
            for (int off = 1; off < 16; off <<= 1) {
                const double ov = __shfl_xor(v, off);
                const int    oi = __shfl_xor(i, off);
                if (ov > v || (ov == v && oi < i)) { v = ov; i = oi; }
            }
            if (lane == 0) {
                s_widx = i;
                idx_out[b * MSEL + k] = i;
            }
        }
        __syncthreads();

        // --- owning thread publishes winner coords (fp32 bits, exact) ---
        const int widx = s_widx;
        if ((widx & 1023) == tid) {
            const int j = widx >> 10;
            const float wx = (float)px[j], wy = (float)py[j], wz = (float)pz[j];
            s_cx = wx; s_cy = wy; s_cz = wz;
            float* o = dp + ((size_t)b * MSEL + k) * 3;
            o[0] = wx; o[1] = wy; o[2] = wz;
        }
        __syncthreads();
        cx = (double)s_cx; cy = (double)s_cy; cz = (double)s_cz;
    }
}

// One wave per selected row; lane i moves one float4 (64 * 16B = 1024B = full row).
__global__ void gather_kernel(const float* __restrict__ feats,  // [B, N, C]
                              const int* __restrict__ idx,      // [B, M]
                              float* __restrict__ df)           // [B, M, C]
{
    const int row  = blockIdx.x * 4 + (threadIdx.x >> 6);  // [0, B*M)
    const int lane = threadIdx.x & 63;
    const int b    = row >> 12;         // MSEL = 4096 rows per batch
    const int src  = idx[row];
    const float4* s = (const float4*)(feats + ((size_t)b * NPTS + src) * NFEAT);
    float4*       d = (float4*)(df + (size_t)row * NFEAT);
    d[lane] = s[lane];
}

extern "C" void kernel_launch(void* const* d_in, const int* in_sizes, int n_in,
                              void* d_out, int out_size, void* d_ws, size_t ws_size,
                              hipStream_t stream)
{
    const float* points   = (const float*)d_in[0];   // [8, 8192, 3]
    const float* features = (const float*)d_in[1];   // [8, 8192, 256]
    float* out = (float*)d_out;
    float* dp  = out;                                // [8, 4096, 3]
    float* df  = out + (size_t)BATCH * MSEL * 3;     // [8, 4096, 256]
    int*   idx_ws = (int*)d_ws;                      // [8, 4096] = 128 KB scratch

    fps_kernel<<<BATCH, BLOCK, 0, stream>>>(points, dp, idx_ws);
    gather_kernel<<<(BATCH * MSEL) / 4, 256, 0, stream>>>(features, idx_ws, df);
}

// Round 4
// 9185.989 us; speedup vs baseline: 1.1406x; 1.1406x over previous
//
#include <hip/hip_runtime.h>

// AdaptiveDownsampling: farthest point sampling (B=8, N=8192, m=4096) + gather.
// Outputs concatenated flat: dp [8,4096,3] then df [8,4096,256], float32.
//
// Round-2 finding: np reference computes in float64 -> selection chain is fp64.
// Round-3 finding: VGPR_Count=48 proved the fp64 arrays were spilled to
// scratch — caused by dynamic register-array indexing in the winner-publish
// step. Fix: winner coords are re-read from an LDS fp32 copy of the points
// (broadcast read; fp32->fp64 cvt is exact), no dynamic indexing anywhere.

#define BATCH 8
#define NPTS  8192
#define MSEL  4096
#define NFEAT 256
#define BLOCK 1024
#define PPT   8        // points per thread = NPTS / BLOCK

// fp64 square, opaque to the compiler so no v_fma_f64 contraction can merge
// the following adds (numpy float64 does separate mul / add / add).
__device__ __forceinline__ double sqd(double x) {
    double r;
    asm("v_mul_f64 %0, %1, %1" : "=v"(r) : "v"(x));
    return r;
}

__launch_bounds__(BLOCK, 1)
__global__ void fps_kernel(const float* __restrict__ pts,   // [B, N, 3]
                           float* __restrict__ dp,          // [B, M, 3]
                           int* __restrict__ idx_out)       // [B, M]
{
    __shared__ float  s_pts[NPTS * 3];   // 96 KB fp32 copy for winner broadcast
    __shared__ double s_wv[16];
    __shared__ int    s_wi[16];
    __shared__ int    s_widx;

    const int b   = blockIdx.x;
    const int tid = threadIdx.x;
    const float* p = pts + (size_t)b * NPTS * 3;

    // One-time: stage fp32 points into LDS, coalesced (24 floats/thread).
    for (int i = tid; i < NPTS * 3; i += BLOCK) s_pts[i] = p[i];

    // All points + running min-distance live in REGISTERS as fp64.
    // (fp32->fp64 cvt exact; all later arithmetic matches numpy float64.)
    double px[PPT], py[PPT], pz[PPT], mind[PPT];
#pragma unroll
    for (int j = 0; j < PPT; ++j) {
        const int n = tid + (j << 10);
        px[j]   = (double)p[n * 3 + 0];
        py[j]   = (double)p[n * 3 + 1];
        pz[j]   = (double)p[n * 3 + 2];
        mind[j] = 1e10;
    }

    // Selection 0 is point 0 (deterministic start).
    double cx = (double)p[0], cy = (double)p[1], cz = (double)p[2];
    if (tid == 0) {
        dp[(size_t)b * MSEL * 3 + 0] = p[0];
        dp[(size_t)b * MSEL * 3 + 1] = p[1];
        dp[(size_t)b * MSEL * 3 + 2] = p[2];
        idx_out[b * MSEL + 0] = 0;
    }

    const int lane = tid & 63;
    const int wid  = tid >> 6;

    __syncthreads();   // s_pts visible

    for (int k = 1; k < MSEL; ++k) {
        // --- fp64 distance update + thread-local argmax (ascending idx, strict >) ---
        double bv = -1.0;
        int    bi = 0x7fffffff;
#pragma unroll
        for (int j = 0; j < PPT; ++j) {
            const double dx = px[j] - cx;
            const double dy = py[j] - cy;
            const double dz = pz[j] - cz;
            const double d  = (sqd(dx) + sqd(dy)) + sqd(dz);  // ((x^2+y^2)+z^2)
            const double m  = fmin(mind[j], d);
            mind[j] = m;
            if (m > bv) { bv = m; bi = tid + (j << 10); }
        }

        // --- wave64 butterfly: lexicographic (max value, then min index) ---
#pragma unroll
        for (int off = 1; off < 64; off <<= 1) {
            const double ov = __shfl_xor(bv, off);
            const int    oi = __shfl_xor(bi, off);
            if (ov > bv || (ov == bv && oi < bi)) { bv = ov; bi = oi; }
        }
        if (lane == 0) { s_wv[wid] = bv; s_wi[wid] = bi; }
        __syncthreads();                                   // barrier 1

        // --- cross-wave reduce on wave 0 (16 partials) ---
        if (wid == 0) {
            double v = (lane < 16) ? s_wv[lane] : -1.0;
            int    i = (lane < 16) ? s_wi[lane] : 0x7fffffff;
#pragma unroll
            for (int off = 1; off < 16; off <<= 1) {
                const double ov = __shfl_xor(v, off);
                const int    oi = __shfl_xor(i, off);
                if (ov > v || (ov == v && oi < i)) { v = ov; i = oi; }
            }
            if (lane == 0) {
                s_widx = i;
                idx_out[b * MSEL + k] = i;
            }
        }
        __syncthreads();                                   // barrier 2

        // --- all threads: broadcast winner coords from LDS (same-addr = free) ---
        const int   widx = s_widx;
        const float wx = s_pts[widx * 3 + 0];
        const float wy = s_pts[widx * 3 + 1];
        const float wz = s_pts[widx * 3 + 2];
        cx = (double)wx; cy = (double)wy; cz = (double)wz;
        if (tid == 0) {
            float* o = dp + ((size_t)b * MSEL + k) * 3;
            o[0] = wx; o[1] = wy; o[2] = wz;
        }
    }
}

// One wave per selected row; lane i moves one float4 (64 * 16B = 1024B = full row).
__global__ void gather_kernel(const float* __restrict__ feats,  // [B, N, C]
                              const int* __restrict__ idx,      // [B, M]
                              float* __restrict__ df)           // [B, M, C]
{
    const int row  = blockIdx.x * 4 + (threadIdx.x >> 6);  // [0, B*M)
    const int lane = threadIdx.x & 63;
    const int b    = row >> 12;         // MSEL = 4096 rows per batch
    const int src  = idx[row];
    const float4* s = (const float4*)(feats + ((size_t)b * NPTS + src) * NFEAT);
    float4*       d = (float4*)(df + (size_t)row * NFEAT);
    d[lane] = s[lane];
}

extern "C" void kernel_launch(void* const* d_in, const int* in_sizes, int n_in,
                              void* d_out, int out_size, void* d_ws, size_t ws_size,
                              hipStream_t stream)
{
    const float* points   = (const float*)d_in[0];   // [8, 8192, 3]
    const float* features = (const float*)d_in[1];   // [8, 8192, 256]
    float* out = (float*)d_out;
    float* dp  = out;                                // [8, 4096, 3]
    float* df  = out + (size_t)BATCH * MSEL * 3;     // [8, 4096, 256]
    int*   idx_ws = (int*)d_ws;                      // [8, 4096] = 128 KB scratch

    fps_kernel<<<BATCH, BLOCK, 0, stream>>>(points, dp, idx_ws);
    gather_kernel<<<(BATCH * MSEL) / 4, 256, 0, stream>>>(features, idx_ws, df);
}

// Round 5
// 6585.830 us; speedup vs baseline: 1.5910x; 1.3948x over previous
//
#include <hip/hip_runtime.h>

// AdaptiveDownsampling: farthest point sampling (B=8, N=8192, m=4096) + gather.
// Outputs concatenated flat: dp [8,4096,3] then df [8,4096,256], float32.
//
// Round-2 finding: np reference computes in float64 -> selection chain is fp64.
// Round-3/4 finding: double ARRAYS never got promoted (VGPR_Count 48/52 < the
// 64 regs the state needs) -> every access was scratch/AGPR traffic, ~5350
// cyc/iter vs ~1300 floor. Round 5: named scalar doubles (no arrays at all)
// + value-only max reduction; index recovered afterwards by equality rescan
// and LDS atomicMin (preserves numpy first-index tie-break exactly).

#define BATCH 8
#define NPTS  8192
#define MSEL  4096
#define NFEAT 256
#define BLOCK 1024

// fp64 square, opaque to the compiler so no v_fma_f64 contraction can merge
// the following adds (numpy float64 does separate mul / add / add).
__device__ __forceinline__ double sqd(double x) {
    double r;
    asm("v_mul_f64 %0, %1, %1" : "=v"(r) : "v"(x));
    return r;
}

__launch_bounds__(BLOCK, 1)
__global__ void fps_kernel(const float* __restrict__ pts,   // [B, N, 3]
                           float* __restrict__ dp,          // [B, M, 3]
                           int* __restrict__ idx_out)       // [B, M]
{
    __shared__ float  s_pts[NPTS * 3];   // 96 KB fp32 copy for winner broadcast
    __shared__ double s_wv[16];          // per-wave maxes
    __shared__ int    s_widx[2];         // double-buffered winner index (atomicMin)

    const int b   = blockIdx.x;
    const int tid = threadIdx.x;
    const float* p = pts + (size_t)b * NPTS * 3;

    // One-time: stage fp32 points into LDS, coalesced.
    for (int i = tid; i < NPTS * 3; i += BLOCK) s_pts[i] = p[i];

    // 8 points/thread + running min-dist as NAMED fp64 scalars -> VGPRs.
    // (fp32->fp64 cvt exact; all later arithmetic matches numpy float64.)
#define DECLPT(J) \
    double px##J = (double)p[(tid + J * 1024) * 3 + 0]; \
    double py##J = (double)p[(tid + J * 1024) * 3 + 1]; \
    double pz##J = (double)p[(tid + J * 1024) * 3 + 2]; \
    double mind##J = 1e10;
    DECLPT(0) DECLPT(1) DECLPT(2) DECLPT(3)
    DECLPT(4) DECLPT(5) DECLPT(6) DECLPT(7)
#undef DECLPT

    // Selection 0 is point 0 (deterministic start).
    double cx = (double)p[0], cy = (double)p[1], cz = (double)p[2];
    if (tid == 0) {
        dp[(size_t)b * MSEL * 3 + 0] = p[0];
        dp[(size_t)b * MSEL * 3 + 1] = p[1];
        dp[(size_t)b * MSEL * 3 + 2] = p[2];
        idx_out[b * MSEL + 0] = 0;
    }

    const int lane = tid & 63;

    for (int k = 1; k < MSEL; ++k) {
        // --- fp64 distance update (exact numpy float64 semantics) ---
#define UPD(J) { \
        const double dx = px##J - cx; \
        const double dy = py##J - cy; \
        const double dz = pz##J - cz; \
        const double d  = (sqd(dx) + sqd(dy)) + sqd(dz); \
        mind##J = fmin(mind##J, d); }
        UPD(0) UPD(1) UPD(2) UPD(3) UPD(4) UPD(5) UPD(6) UPD(7)
#undef UPD

        // --- thread-local max (value only, balanced tree) ---
        const double a0 = fmax(mind0, mind1), a1 = fmax(mind2, mind3);
        const double a2 = fmax(mind4, mind5), a3 = fmax(mind6, mind7);
        const double tbv = fmax(fmax(a0, a1), fmax(a2, a3));

        // --- wave64 butterfly max (value only) ---
        double bv = tbv;
#pragma unroll
        for (int off = 1; off < 64; off <<= 1)
            bv = fmax(bv, __shfl_xor(bv, off));

        if (lane == 0) s_wv[tid >> 6] = bv;
        if (tid == 0)  s_widx[k & 1] = 0x7fffffff;   // reset this iter's slot
        __syncthreads();                             // barrier A

        // --- block max: every thread reduces the 16 wave maxes (broadcast) ---
        double t0 = fmax(s_wv[0],  s_wv[1]);
        double t1 = fmax(s_wv[2],  s_wv[3]);
        double t2 = fmax(s_wv[4],  s_wv[5]);
        double t3 = fmax(s_wv[6],  s_wv[7]);
        double t4 = fmax(s_wv[8],  s_wv[9]);
        double t5 = fmax(s_wv[10], s_wv[11]);
        double t6 = fmax(s_wv[12], s_wv[13]);
        double t7 = fmax(s_wv[14], s_wv[15]);
        t0 = fmax(t0, t1); t2 = fmax(t2, t3);
        t4 = fmax(t4, t5); t6 = fmax(t6, t7);
        const double bmax = fmax(fmax(t0, t2), fmax(t4, t6));

        // --- owners (local max == block max) publish first matching index ---
        if (tbv == bmax) {
            int li = 7;
            li = (mind6 == tbv) ? 6 : li;
            li = (mind5 == tbv) ? 5 : li;
            li = (mind4 == tbv) ? 4 : li;
            li = (mind3 == tbv) ? 3 : li;
            li = (mind2 == tbv) ? 2 : li;
            li = (mind1 == tbv) ? 1 : li;
            li = (mind0 == tbv) ? 0 : li;
            atomicMin(&s_widx[k & 1], tid + (li << 10));  // global idx = tid + j*1024
        }
        __syncthreads();                             // barrier B

        // --- all threads: broadcast winner coords from LDS (same-addr = free) ---
        const int   widx = s_widx[k & 1];
        const float wx = s_pts[widx * 3 + 0];
        const float wy = s_pts[widx * 3 + 1];
        const float wz = s_pts[widx * 3 + 2];
        if (tid == 0) {
            idx_out[b * MSEL + k] = widx;
            float* o = dp + ((size_t)b * MSEL + k) * 3;
            o[0] = wx; o[1] = wy; o[2] = wz;
        }
        cx = (double)wx; cy = (double)wy; cz = (double)wz;
    }
}

// One wave per selected row; lane i moves one float4 (64 * 16B = 1024B = full row).
__global__ void gather_kernel(const float* __restrict__ feats,  // [B, N, C]
                              const int* __restrict__ idx,      // [B, M]
                              float* __restrict__ df)           // [B, M, C]
{
    const int row  = blockIdx.x * 4 + (threadIdx.x >> 6);  // [0, B*M)
    const int lane = threadIdx.x & 63;
    const int b    = row >> 12;         // MSEL = 4096 rows per batch
    const int src  = idx[row];
    const float4* s = (const float4*)(feats + ((size_t)b * NPTS + src) * NFEAT);
    float4*       d = (float4*)(df + (size_t)row * NFEAT);
    d[lane] = s[lane];
}

extern "C" void kernel_launch(void* const* d_in, const int* in_sizes, int n_in,
                              void* d_out, int out_size, void* d_ws, size_t ws_size,
                              hipStream_t stream)
{
    const float* points   = (const float*)d_in[0];   // [8, 8192, 3]
    const float* features = (const float*)d_in[1];   // [8, 8192, 256]
    float* out = (float*)d_out;
    float* dp  = out;                                // [8, 4096, 3]
    float* df  = out + (size_t)BATCH * MSEL * 3;     // [8, 4096, 256]
    int*   idx_ws = (int*)d_ws;                      // [8, 4096] = 128 KB scratch

    fps_kernel<<<BATCH, BLOCK, 0, stream>>>(points, dp, idx_ws);
    gather_kernel<<<(BATCH * MSEL) / 4, 256, 0, stream>>>(features, idx_ws, df);
}

// Round 6
// 5275.054 us; speedup vs baseline: 1.9863x; 1.2485x over previous
//
#include <hip/hip_runtime.h>

// AdaptiveDownsampling: farthest point sampling (B=8, N=8192, m=4096) + gather.
// Outputs concatenated flat: dp [8,4096,3] then df [8,4096,256], float32.
//
// r2: np reference computes in float64 -> exact path must be fp64.
// r3/r4/r5: BLOCK=1024 caps regs at 128/lane; pure-fp64 state (64+ regs)
//   got parked in AGPRs (VGPR_Count 48/52/60) -> accvgpr tax on 33.5M evals.
// r6: fp32 screen + rare exact-fp64 path. mind=min(mind,d) changes for only
//   ~68K of 33.5M evals (N*ln m); screen `d_f32 < mf*1.0001f` is sound
//   (nonneg terms, rel err <=6e-7 << 1e-4 margin), so skipping is exact.
//   tbv cached per thread; block max via u64-bits atomicMax (nonneg doubles
//   are order-isomorphic to u64). fp64 state now 16 regs -> fits in VGPRs.

#define BATCH 8
#define NPTS  8192
#define MSEL  4096
#define NFEAT 256
#define BLOCK 1024

// fp64 square, opaque to the compiler so no v_fma_f64 contraction can merge
// the following adds (numpy float64 does separate mul / add / add).
__device__ __forceinline__ double sqd(double x) {
    double r;
    asm("v_mul_f64 %0, %1, %1" : "=v"(r) : "v"(x));
    return r;
}

__launch_bounds__(BLOCK, 1)
__global__ void fps_kernel(const float* __restrict__ pts,   // [B, N, 3]
                           float* __restrict__ dp,          // [B, M, 3]
                           int* __restrict__ idx_out)       // [B, M]
{
    __shared__ float s_pts[NPTS * 3];          // 96 KB fp32 copy (winner broadcast)
    __shared__ unsigned long long s_bmax[2];   // block max, double bits (nonneg)
    __shared__ int s_widx[2];                  // winner index via atomicMin

    const int b   = blockIdx.x;
    const int tid = threadIdx.x;
    const float* p = pts + (size_t)b * NPTS * 3;

    for (int i = tid; i < NPTS * 3; i += BLOCK) s_pts[i] = p[i];
    if (tid == 0) {
        s_bmax[0] = 0ull;        s_bmax[1] = 0ull;
        s_widx[0] = 0x7fffffff;  s_widx[1] = 0x7fffffff;
    }

    // Per-thread state: fp32 coords + fp32 shadow of mind (screen),
    // fp64 mind (exact). Named scalars only -> VGPRs.
#define DECLPT(J) \
    float  px##J = p[(tid + J * 1024) * 3 + 0]; \
    float  py##J = p[(tid + J * 1024) * 3 + 1]; \
    float  pz##J = p[(tid + J * 1024) * 3 + 2]; \
    double mind##J = 1e10; \
    float  mf##J = 1e10f;
    DECLPT(0) DECLPT(1) DECLPT(2) DECLPT(3)
    DECLPT(4) DECLPT(5) DECLPT(6) DECLPT(7)
#undef DECLPT

    // Selection 0 is point 0 (deterministic start).
    float cx = p[0], cy = p[1], cz = p[2];
    if (tid == 0) {
        dp[(size_t)b * MSEL * 3 + 0] = cx;
        dp[(size_t)b * MSEL * 3 + 1] = cy;
        dp[(size_t)b * MSEL * 3 + 2] = cz;
        idx_out[b * MSEL + 0] = 0;
    }

    const int lane = tid & 63;
    double tbv   = 0.0;     // cached thread-local max of mind0..7
    bool   dirty = true;

    __syncthreads();   // s_pts + slot inits visible

    for (int k = 1; k < MSEL; ++k) {
        const double cxd = (double)cx, cyd = (double)cy, czd = (double)cz;

        // --- fp32 screen; exact fp64 update only when the min could change ---
#define UPD(J) { \
        const float fdx = px##J - cx, fdy = py##J - cy, fdz = pz##J - cz; \
        const float df32 = fdx * fdx + fdy * fdy + fdz * fdz; \
        if (df32 < mf##J * 1.0001f) { \
            const double dx = (double)px##J - cxd; \
            const double dy = (double)py##J - cyd; \
            const double dz = (double)pz##J - czd; \
            const double d  = (sqd(dx) + sqd(dy)) + sqd(dz); \
            if (d < mind##J) { mind##J = d; mf##J = (float)d; dirty = true; } \
        } }
        UPD(0) UPD(1) UPD(2) UPD(3) UPD(4) UPD(5) UPD(6) UPD(7)
#undef UPD

        // --- thread-local max, recomputed only when a slot changed ---
        if (dirty) {
            const double a0 = fmax(mind0, mind1), a1 = fmax(mind2, mind3);
            const double a2 = fmax(mind4, mind5), a3 = fmax(mind6, mind7);
            tbv = fmax(fmax(a0, a1), fmax(a2, a3));
            dirty = false;
        }

        // --- wave64 butterfly max, then per-wave atomicMax of double bits ---
        double bv = tbv;
#pragma unroll
        for (int off = 1; off < 64; off <<= 1)
            bv = fmax(bv, __shfl_xor(bv, off));
        if (lane == 0)
            atomicMax(&s_bmax[k & 1], (unsigned long long)__double_as_longlong(bv));
        __syncthreads();                                   // barrier A

        const unsigned long long bmaxbits = s_bmax[k & 1];
        if (tid == 0) {   // reset NEXT iter's slots: ordered by A before, B after
            s_bmax[(k + 1) & 1] = 0ull;
            s_widx[(k + 1) & 1] = 0x7fffffff;
        }

        // --- owners publish first matching global index (numpy tie-break) ---
        if ((unsigned long long)__double_as_longlong(tbv) == bmaxbits) {
            int n = 0x7fffffff;
            if (mind7 == tbv) n = tid + 7 * 1024;
            if (mind6 == tbv) n = tid + 6 * 1024;
            if (mind5 == tbv) n = tid + 5 * 1024;
            if (mind4 == tbv) n = tid + 4 * 1024;
            if (mind3 == tbv) n = tid + 3 * 1024;
            if (mind2 == tbv) n = tid + 2 * 1024;
            if (mind1 == tbv) n = tid + 1 * 1024;
            if (mind0 == tbv) n = tid;
            atomicMin(&s_widx[k & 1], n);
        }
        __syncthreads();                                   // barrier B

        // --- broadcast winner coords from LDS (same-addr = conflict-free) ---
        const int   widx = s_widx[k & 1];
        const float wx = s_pts[widx * 3 + 0];
        const float wy = s_pts[widx * 3 + 1];
        const float wz = s_pts[widx * 3 + 2];
        if (tid == 0) {
            idx_out[b * MSEL + k] = widx;
            float* o = dp + ((size_t)b * MSEL + k) * 3;
            o[0] = wx; o[1] = wy; o[2] = wz;
        }
        cx = wx; cy = wy; cz = wz;
    }
}

// One wave per selected row; lane i moves one float4 (64 * 16B = 1024B = full row).
__global__ void gather_kernel(const float* __restrict__ feats,  // [B, N, C]
                              const int* __restrict__ idx,      // [B, M]
                              float* __restrict__ df)           // [B, M, C]
{
    const int row  = blockIdx.x * 4 + (threadIdx.x >> 6);  // [0, B*M)
    const int lane = threadIdx.x & 63;
    const int b    = row >> 12;         // MSEL = 4096 rows per batch
    const int src  = idx[row];
    const float4* s = (const float4*)(feats + ((size_t)b * NPTS + src) * NFEAT);
    float4*       d = (float4*)(df + (size_t)row * NFEAT);
    d[lane] = s[lane];
}

extern "C" void kernel_launch(void* const* d_in, const int* in_sizes, int n_in,
                              void* d_out, int out_size, void* d_ws, size_t ws_size,
                              hipStream_t stream)
{
    const float* points   = (const float*)d_in[0];   // [8, 8192, 3]
    const float* features = (const float*)d_in[1];   // [8, 8192, 256]
    float* out = (float*)d_out;
    float* dp  = out;                                // [8, 4096, 3]
    float* df  = out + (size_t)BATCH * MSEL * 3;     // [8, 4096, 256]
    int*   idx_ws = (int*)d_ws;                      // [8, 4096] = 128 KB scratch

    fps_kernel<<<BATCH, BLOCK, 0, stream>>>(points, dp, idx_ws);
    gather_kernel<<<(BATCH * MSEL) / 4, 256, 0, stream>>>(features, idx_ws, df);
}

// Round 7
// 4239.107 us; speedup vs baseline: 2.4717x; 1.2444x over previous
//
#include <hip/hip_runtime.h>

// AdaptiveDownsampling: farthest point sampling (B=8, N=8192, m=4096) + gather.
// Outputs concatenated flat: dp [8,4096,3] then df [8,4096,256], float32.
//
// r2: np reference computes in float64 -> exact path must be fp64.
// r3-r5: register-array spill / AGPR tax lessons; named scalars only.
// r6: fp32 screen + rare exact fp64 path (sound: nonneg terms, rel err
//     <=1.1e-6 << 1e-4 margin). 5275 us; ~3050 cyc/iter, ~half serial stall.
// r7: (a) wave max via VALU-only DPP (row_shr 1/2/4/8 + row_bcast 15/31,
//     two u32 passes = exact u64 max of nonneg double bits) replacing the
//     ds_bpermute fp64 butterfly (~600 cyc of LDS round-trip latency);
//     (b) packed-fp32 screen via float2 (v_pk_add/fma_f32, full-rate);
//     (c) mfm = mf*1.0001f precomputed on update, not per screen.

typedef float v2f __attribute__((ext_vector_type(2)));

#define BATCH 8
#define NPTS  8192
#define MSEL  4096
#define NFEAT 256
#define BLOCK 1024

// fp64 square, opaque to the compiler so no v_fma_f64 contraction can merge
// the following adds (numpy float64 does separate mul / add / add).
__device__ __forceinline__ double sqd(double x) {
    double r;
    asm("v_mul_f64 %0, %1, %1" : "=v"(r) : "v"(x));
    return r;
}

// Exact 64-lane u32 max, VALU-only (DPP), result broadcast via lane 63.
// Canonical gfx9 sequence; invalid-source lanes contribute old=0 (safe: all
// inputs nonneg). Uniform control flow required at call site.
__device__ __forceinline__ unsigned wave_umax(unsigned v) {
    unsigned t;
    t = (unsigned)__builtin_amdgcn_update_dpp(0, (int)v, 0x111, 0xf, 0xf, false); v = v > t ? v : t; // row_shr:1
    t = (unsigned)__builtin_amdgcn_update_dpp(0, (int)v, 0x112, 0xf, 0xf, false); v = v > t ? v : t; // row_shr:2
    t = (unsigned)__builtin_amdgcn_update_dpp(0, (int)v, 0x114, 0xf, 0xf, false); v = v > t ? v : t; // row_shr:4
    t = (unsigned)__builtin_amdgcn_update_dpp(0, (int)v, 0x118, 0xf, 0xf, false); v = v > t ? v : t; // row_shr:8
    t = (unsigned)__builtin_amdgcn_update_dpp(0, (int)v, 0x142, 0xf, 0xf, false); v = v > t ? v : t; // row_bcast:15
    t = (unsigned)__builtin_amdgcn_update_dpp(0, (int)v, 0x143, 0xf, 0xf, false); v = v > t ? v : t; // row_bcast:31
    return (unsigned)__builtin_amdgcn_readlane((int)v, 63);
}

__launch_bounds__(BLOCK, 1)
__global__ void fps_kernel(const float* __restrict__ pts,   // [B, N, 3]
                           float* __restrict__ dp,          // [B, M, 3]
                           int* __restrict__ idx_out)       // [B, M]
{
    __shared__ float s_pts[NPTS * 3];          // 96 KB fp32 copy (winner broadcast)
    __shared__ unsigned long long s_bmax[2];   // block max, double bits (nonneg)
    __shared__ int s_widx[2];                  // winner index via atomicMin

    const int b   = blockIdx.x;
    const int tid = threadIdx.x;
    const float* p = pts + (size_t)b * NPTS * 3;

    for (int i = tid; i < NPTS * 3; i += BLOCK) s_pts[i] = p[i];
    if (tid == 0) {
        s_bmax[0] = 0ull;        s_bmax[1] = 0ull;
        s_widx[0] = 0x7fffffff;  s_widx[1] = 0x7fffffff;
    }

    // Coords as float2 pairs (slots 2P, 2P+1) -> packed-fp32 screen.
    // mind (fp64 exact) + mfm (pre-margined fp32 screen threshold) per slot.
#define DECLP(P, J0, J1) \
    v2f pxp##P = { p[(tid + J0 * 1024) * 3 + 0], p[(tid + J1 * 1024) * 3 + 0] }; \
    v2f pyp##P = { p[(tid + J0 * 1024) * 3 + 1], p[(tid + J1 * 1024) * 3 + 1] }; \
    v2f pzp##P = { p[(tid + J0 * 1024) * 3 + 2], p[(tid + J1 * 1024) * 3 + 2] };
    DECLP(0, 0, 1) DECLP(1, 2, 3) DECLP(2, 4, 5) DECLP(3, 6, 7)
#undef DECLP
    double mind0 = 1e10, mind1 = 1e10, mind2 = 1e10, mind3 = 1e10;
    double mind4 = 1e10, mind5 = 1e10, mind6 = 1e10, mind7 = 1e10;
    float  mfm0 = 1.0001e10f, mfm1 = 1.0001e10f, mfm2 = 1.0001e10f, mfm3 = 1.0001e10f;
    float  mfm4 = 1.0001e10f, mfm5 = 1.0001e10f, mfm6 = 1.0001e10f, mfm7 = 1.0001e10f;

    // Selection 0 is point 0 (deterministic start).
    float cx = p[0], cy = p[1], cz = p[2];
    if (tid == 0) {
        dp[(size_t)b * MSEL * 3 + 0] = cx;
        dp[(size_t)b * MSEL * 3 + 1] = cy;
        dp[(size_t)b * MSEL * 3 + 2] = cz;
        idx_out[b * MSEL + 0] = 0;
    }

    const int lane = tid & 63;
    double tbv   = 0.0;     // cached thread-local max of mind0..7
    bool   dirty = true;

    __syncthreads();   // s_pts + slot inits visible

    for (int k = 1; k < MSEL; ++k) {
        const double cxd = (double)cx, cyd = (double)cy, czd = (double)cz;
        const v2f cx2 = {cx, cx}, cy2 = {cy, cy}, cz2 = {cz, cz};

        // --- packed fp32 screen; exact fp64 update only on trigger ---
#define EX64(PX, PY, PZ, J) { \
        const double ddx = (double)(PX) - cxd; \
        const double ddy = (double)(PY) - cyd; \
        const double ddz = (double)(PZ) - czd; \
        const double dd  = (sqd(ddx) + sqd(ddy)) + sqd(ddz); \
        if (dd < mind##J) { mind##J = dd; mfm##J = (float)dd * 1.0001f; dirty = true; } }
#define UPDP(P, J0, J1) { \
        const v2f dx = pxp##P - cx2, dy = pyp##P - cy2, dz = pzp##P - cz2; \
        const v2f d  = dx * dx + dy * dy + dz * dz; \
        if (d.x < mfm##J0) EX64(pxp##P.x, pyp##P.x, pzp##P.x, J0) \
        if (d.y < mfm##J1) EX64(pxp##P.y, pyp##P.y, pzp##P.y, J1) }
        UPDP(0, 0, 1) UPDP(1, 2, 3) UPDP(2, 4, 5) UPDP(3, 6, 7)
#undef UPDP
#undef EX64

        // --- thread-local max, recomputed only when a slot changed ---
        if (dirty) {
            const double a0 = fmax(mind0, mind1), a1 = fmax(mind2, mind3);
            const double a2 = fmax(mind4, mind5), a3 = fmax(mind6, mind7);
            tbv = fmax(fmax(a0, a1), fmax(a2, a3));
            dirty = false;
        }

        // --- wave max of nonneg double bits: two u32 DPP passes (exact) ---
        const unsigned long long tb = (unsigned long long)__double_as_longlong(tbv);
        const unsigned thi  = (unsigned)(tb >> 32);
        const unsigned hmax = wave_umax(thi);
        const unsigned lpart = (thi == hmax) ? (unsigned)tb : 0u;
        const unsigned lmax = wave_umax(lpart);
        if (lane == 0)
            atomicMax(&s_bmax[k & 1],
                      ((unsigned long long)hmax << 32) | (unsigned long long)lmax);
        __syncthreads();                                   // barrier A

        const unsigned long long bmaxbits = s_bmax[k & 1];
        if (tid == 0) {   // reset NEXT iter's slots (between barriers A and B)
            s_bmax[(k + 1) & 1] = 0ull;
            s_widx[(k + 1) & 1] = 0x7fffffff;
        }

        // --- owners publish first matching global index (numpy tie-break) ---
        if ((unsigned long long)__double_as_longlong(tbv) == bmaxbits) {
            int n = 0x7fffffff;
            if (mind7 == tbv) n = tid + 7 * 1024;
            if (mind6 == tbv) n = tid + 6 * 1024;
            if (mind5 == tbv) n = tid + 5 * 1024;
            if (mind4 == tbv) n = tid + 4 * 1024;
            if (mind3 == tbv) n = tid + 3 * 1024;
            if (mind2 == tbv) n = tid + 2 * 1024;
            if (mind1 == tbv) n = tid + 1 * 1024;
            if (mind0 == tbv) n = tid;
            atomicMin(&s_widx[k & 1], n);
        }
        __syncthreads();                                   // barrier B

        // --- broadcast winner coords from LDS (same-addr = conflict-free) ---
        const int   widx = s_widx[k & 1];
        const float wx = s_pts[widx * 3 + 0];
        const float wy = s_pts[widx * 3 + 1];
        const float wz = s_pts[widx * 3 + 2];
        if (tid == 0) {
            idx_out[b * MSEL + k] = widx;
            float* o = dp + ((size_t)b * MSEL + k) * 3;
            o[0] = wx; o[1] = wy; o[2] = wz;
        }
        cx = wx; cy = wy; cz = wz;
    }
}

// One wave per selected row; lane i moves one float4 (64 * 16B = 1024B = full row).
__global__ void gather_kernel(const float* __restrict__ feats,  // [B, N, C]
                              const int* __restrict__ idx,      // [B, M]
                              float* __restrict__ df)           // [B, M, C]
{
    const int row  = blockIdx.x * 4 + (threadIdx.x >> 6);  // [0, B*M)
    const int lane = threadIdx.x & 63;
    const int b    = row >> 12;         // MSEL = 4096 rows per batch
    const int src  = idx[row];
    const float4* s = (const float4*)(feats + ((size_t)b * NPTS + src) * NFEAT);
    float4*       d = (float4*)(df + (size_t)row * NFEAT);
    d[lane] = s[lane];
}

extern "C" void kernel_launch(void* const* d_in, const int* in_sizes, int n_in,
                              void* d_out, int out_size, void* d_ws, size_t ws_size,
                              hipStream_t stream)
{
    const float* points   = (const float*)d_in[0];   // [8, 8192, 3]
    const float* features = (const float*)d_in[1];   // [8, 8192, 256]
    float* out = (float*)d_out;
    float* dp  = out;                                // [8, 4096, 3]
    float* df  = out + (size_t)BATCH * MSEL * 3;     // [8, 4096, 256]
    int*   idx_ws = (int*)d_ws;                      // [8, 4096] = 128 KB scratch

    fps_kernel<<<BATCH, BLOCK, 0, stream>>>(points, dp, idx_ws);
    gather_kernel<<<(BATCH * MSEL) / 4, 256, 0, stream>>>(features, idx_ws, df);
}